// Round 13
// baseline (209.071 us; speedup 1.0000x reference)
//
#include <hip/hip_runtime.h>
#include <hip/hip_fp16.h>

#define B_  4
#define C_  16
#define H_  256
#define W_  256
#define CO_ 16
#define KS_ 3
#define KK_ 9
#define HW_ (H_ * W_)
// ws layout (u32 words): fp8 image, TWO half-planes of 8 B/pixel | kbuf |
// partials (float) | done-counters (u32)
#define IMG_WORDS ((size_t)B_ * HW_ * 4)   // 16 B per pixel total (fp8 e4m3)
#define KER_OFF   IMG_WORDS
#define NKB 5                               // k-blocks per group: K=160
#define NBLK 2048                           // blocks: 128 pixels each
#define PART_OFF (KER_OFF + (size_t)NKB * 256)
#define CNT_OFF  (PART_OFF + NBLK)          // 33 counters (32 group + 1 glob)

typedef _Float16 f16x8 __attribute__((ext_vector_type(8)));
typedef __fp16   fp16x2 __attribute__((ext_vector_type(2)));  // cvt_pkrtz ret
typedef float    f32x2v __attribute__((ext_vector_type(2)));
typedef __attribute__((ext_vector_type(4))) float f32x4;
union U4H8 { uint4 u; f16x8 h; };

// 16B load from an 8B-aligned address (pair of adjacent 8B half-records).
__device__ __forceinline__ uint4 ld16(const uint2* p) {
    uint4 r; __builtin_memcpy(&r, p, sizeof(uint4)); return r;
}

// ------- Kernel 1: NCHW fp32 -> fp8 HALF-PLANE pack (4 px/thread) ----------
// Image stored as two planes: plane h holds channels [8h, 8h+8) of every
// pixel, 8 B/pixel contiguous -> deform fetches each bilinear x-pair with
// ONE dwordx4 (r12 win: transaction count, not bytes, bounds deform).
// 4 pixels/thread with float4 plane loads: 16 dwordx4 loads + 4 dwordx4
// stores replace 64 scalar loads + 8 stores (pack was instruction-limited).
// Block mapping XCD-aligned with deform (same bx&7 bijection).
// Also zeroes the done-counters used by deform's fused final reduction.
__global__ __launch_bounds__(256) void pack_nhwc_fp8(
    const float* __restrict__ inp, const float* __restrict__ ker,
    unsigned* __restrict__ wsu)
{
    const int t = threadIdx.x;
    // bijection on [0,256): XCD x=bx&7 covers 1024-px chunks [x*32,(x+1)*32)
    const int j = (blockIdx.x & 7) * 32 + (blockIdx.x >> 3);
    const int e = j * 1024 + t * 4;         // first of this thread's 4 pixels
    const int b = e >> 16;
    const int hw = e & (HW_ - 1);
    const float* src = inp + (size_t)b * (C_ * HW_) + hw;
    f32x4 v[C_];
#pragma unroll
    for (int c = 0; c < C_; c++)
        v[c] = *(const f32x4*)(src + (size_t)c * HW_);   // 16 B coalesced
    unsigned pw0[8], pw1[8];
#pragma unroll
    for (int p = 0; p < 4; p++) {
        unsigned u[4];
#pragma unroll
        for (int d = 0; d < 4; d++) {
            unsigned w = 0;
            w = __builtin_amdgcn_cvt_pk_fp8_f32(v[4*d+0][p], v[4*d+1][p], w, false);
            w = __builtin_amdgcn_cvt_pk_fp8_f32(v[4*d+2][p], v[4*d+3][p], w, true);
            u[d] = w;
        }
        pw0[2*p] = u[0]; pw0[2*p+1] = u[1];   // plane 0: ch 0-7
        pw1[2*p] = u[2]; pw1[2*p+1] = u[3];   // plane 1: ch 8-15
    }
    uint4* d0 = (uint4*)((uint2*)wsu + e);
    d0[0] = make_uint4(pw0[0], pw0[1], pw0[2], pw0[3]);
    d0[1] = make_uint4(pw0[4], pw0[5], pw0[6], pw0[7]);
    uint4* d1 = (uint4*)((uint2*)wsu + (size_t)B_ * HW_ + e);
    d1[0] = make_uint4(pw1[0], pw1[1], pw1[2], pw1[3]);
    d1[1] = make_uint4(pw1[4], pw1[5], pw1[6], pw1[7]);

    if (blockIdx.x == 0) {
        if (t < 33) wsu[CNT_OFF + t] = 0u;  // done-counters (kernel-boundary
                                            // flush makes this visible)
        // kbuf: f16 B-fragment layout for mfma_f32_16x16x32_f16 (unchanged).
        for (int i = t; i < NKB * 256; i += 256) {
            const int wj  = i & 3;
            const int l   = (i >> 2) & 63;
            const int blk = i >> 8;
            const int o   = l & 15;
            unsigned lo = 0, hi = 0;
            {
                int jj = 2 * wj, k = (l >> 4) * 8 + jj;
                int tap = 2 * blk + (k >> 4), c = k & 15;
                if (tap <= 8) {
                    __half hh = __float2half(ker[(o * C_ + c) * KK_ + tap]);
                    lo = __half_as_ushort(hh);
                }
                jj = 2 * wj + 1; k = (l >> 4) * 8 + jj;
                tap = 2 * blk + (k >> 4); c = k & 15;
                if (tap <= 8) {
                    __half hh = __float2half(ker[(o * C_ + c) * KK_ + tap]);
                    hi = __half_as_ushort(hh);
                }
            }
            wsu[KER_OFF + i] = lo | (hi << 16);
        }
    }
}

// ------- tap setup, pair form (r12, unchanged) ------------------------------
__device__ __forceinline__ void tap_setup_pair(
    int h, int w, int kk, float dy, float dx,
    int* ridx, float* wt)
{
    const float y = dy + (float)(h - 1 + kk / KS_);
    const float x = dx + (float)(w - 1 + kk % KS_);
    const float y0f = floorf(y);
    const float x0f = floorf(x);
    const int   y0  = (int)y0f;
    const int   x0  = (int)x0f;
    const float wy  = y - y0f;
    const float wx  = x - x0f;

    float w00 = (1.f - wy) * (1.f - wx);
    float w01 = (1.f - wy) * wx;
    float w10 = wy * (1.f - wx);
    float w11 = wy * wx;

    const bool v0y = ((unsigned)y0       < (unsigned)H_);
    const bool v1y = ((unsigned)(y0 + 1) < (unsigned)H_);
    const bool v0x = ((unsigned)x0       < (unsigned)W_);
    const bool v1x = ((unsigned)(x0 + 1) < (unsigned)W_);

    w00 = (v0y & v0x) ? w00 : 0.f;
    w01 = (v0y & v1x) ? w01 : 0.f;
    w10 = (v1y & v0x) ? w10 : 0.f;
    w11 = (v1y & v1x) ? w11 : 0.f;

    const int  p    = min(max(x0, 0), W_ - 2);
    const bool s0hi = (x0 >= W_ - 1);   // corner x0   -> hi slot (right edge)
    const bool s1lo = (x0 <= -1);       // corner x0+1 -> lo slot (left edge)

    wt[0] = (s0hi ? 0.f : w00) + (s1lo ? w01 : 0.f);
    wt[1] = (s0hi ? w00 : 0.f) + (s1lo ? 0.f : w01);
    wt[2] = (s0hi ? 0.f : w10) + (s1lo ? w11 : 0.f);
    wt[3] = (s0hi ? w10 : 0.f) + (s1lo ? 0.f : w11);

    const int y0c = min(max(y0,     0), H_ - 1);
    const int y1c = min(max(y0 + 1, 0), H_ - 1);
    ridx[0] = y0c * W_ + p;
    ridx[1] = y1c * W_ + p;
}

// fp8 corner blend, one output word (2 channels): 4 cvt_pk_f32_fp8 +
// 8 f32 fma + 1 cvt_pkrtz. f32 blend = single rounding.
template<bool HI>
__device__ __forceinline__ unsigned blend2_fp8(
    unsigned a, unsigned b, unsigned c, unsigned d,
    float w0, float w1, float w2, float w3)
{
    const f32x2v va = __builtin_amdgcn_cvt_pk_f32_fp8(a, HI);
    const f32x2v vb = __builtin_amdgcn_cvt_pk_f32_fp8(b, HI);
    const f32x2v vc = __builtin_amdgcn_cvt_pk_f32_fp8(c, HI);
    const f32x2v vd = __builtin_amdgcn_cvt_pk_f32_fp8(d, HI);
    const float rl = w0 * va.x + w1 * vb.x + w2 * vc.x + w3 * vd.x;
    const float rh = w0 * va.y + w1 * vb.y + w2 * vc.y + w3 * vd.y;
    union { fp16x2 h; unsigned u; } cv;
    cv.h = __builtin_amdgcn_cvt_pkrtz(rl, rh);
    return cv.u;
}

// ------- Kernel 2: deform-conv + MSE + FUSED final reduction ---------------
// Wave = 2 groups x 16 pixels x 4 k-quads; pair-gather (r12); prefetch-2
// (r7). Ending: each block release-stores its partial, then hierarchical
// done-counters (32 group x 64 incs + 1 global x 32 incs — spreads the r2
// same-address burst 64-way); the LAST block acquire-loads all partials and
// writes out[0]. Device-scope atomics per G16 (cross-XCD L2 non-coherence);
// no spinning -> no deadlock. Saves the third dispatch + its gap.
__global__ __launch_bounds__(256) void deform_loss_mfma(
    const float* __restrict__ off, const unsigned* __restrict__ wsu,
    const float* __restrict__ tgt, float* __restrict__ partials,
    float* __restrict__ out)
{
    // XCD swizzle: bijection on [0,2048); xcd = blk&7 covers 256 consecutive
    // 128-pixel blocks = 128 contiguous rows -> per-XCD L2 locality
    const int f = (blockIdx.x & 7) * 256 + (blockIdx.x >> 3);
    const int t = threadIdx.x;
    const int l = t & 63;
    const int q = l >> 4;
    const int m = l & 15;
    const int base = f * 128 + (t >> 6) * 32;   // wave's 32-pixel span
    const int b    = base >> 16;                // span never crosses b
    const int hwb  = base & (HW_ - 1);
    const int h    = hwb >> 8;                  // same row for both groups
    const int w0   = (hwb & (W_ - 1)) + m;      // group g pixel w = w0+16g

    const float* offp = off + (size_t)b * (2 * KK_ * HW_) + (size_t)h * W_;
    const uint2* ibh  = (const uint2*)wsu
                      + (size_t)(q & 1) * (B_ * HW_) + (size_t)b * HW_;
    const uint4* kb   = (const uint4*)(wsu + KER_OFF);

    // B-fragments: 5 x 16 B f16, register-resident (unchanged)
    f16x8 bfr[NKB];
#pragma unroll
    for (int kbk = 0; kbk < NKB; kbk++) {
        U4H8 cv; cv.u = kb[kbk * 64 + l];
        bfr[kbk] = cv.h;
    }

    // ALL entry loads issued together: 20 offsets + 2 target float4s.
    float dyv[2][NKB], dxv[2][NKB];
#pragma unroll
    for (int g = 0; g < 2; g++)
#pragma unroll
        for (int kbk = 0; kbk < NKB; kbk++) {
            const int tap = min(2 * kbk + (q >> 1), KK_ - 1);
            dyv[g][kbk] = offp[(size_t)(2 * tap) * HW_ + w0 + 16 * g];
            dxv[g][kbk] = offp[(size_t)(2 * tap + 1) * HW_ + w0 + 16 * g];
        }
    // targets (C/D layout: col=lane&15=o, row=4q+reg=pixel-in-group)
    const float* tbase = tgt + (size_t)b * (CO_ * HW_) + (size_t)m * HW_
                       + hwb + 4 * q;
    const float4 tv0 = *(const float4*)(tbase);
    const float4 tv1 = *(const float4*)(tbase + 16);

    f32x4 acc[2] = {{0.f, 0.f, 0.f, 0.f}, {0.f, 0.f, 0.f, 0.f}};
    uint4 cor[3][2];        // [slot][row]: .xy = lo record, .zw = hi record
    float wts[3][4];

#define PREP(KBI, SLOT) do {                                               \
        const int gn_ = (KBI) / NKB, kn_ = (KBI) % NKB;                    \
        int ridx_[2];                                                      \
        tap_setup_pair(h, w0 + 16 * gn_, min(2 * kn_ + (q >> 1), KK_ - 1), \
                       dyv[gn_][kn_], dxv[gn_][kn_], ridx_, wts[SLOT]);    \
        if (kn_ == NKB - 1 && (q >> 1) != 0) {                             \
            wts[SLOT][0] = 0.f; wts[SLOT][1] = 0.f;                        \
            wts[SLOT][2] = 0.f; wts[SLOT][3] = 0.f;                        \
            ridx_[0] = 0; ridx_[1] = 0;                                    \
        }                                                                  \
        cor[SLOT][0] = ld16(ibh + ridx_[0]);                               \
        cor[SLOT][1] = ld16(ibh + ridx_[1]);                               \
    } while (0)

    // prologue: fill slots 0 and 1 (kbi = 0, 1 — never padding blocks)
    PREP(0, 0);
    PREP(1, 1);

#pragma unroll
    for (int kbi = 0; kbi < 2 * NKB; kbi++) {
        const int cur = kbi % 3;
        if (kbi + 2 < 2 * NKB)
            PREP(kbi + 2, (kbi + 2) % 3);

        const int g = kbi / NKB;
        const int kkb = kbi % NKB;
        const float wlt = wts[cur][0], wht = wts[cur][1],
                    wlb = wts[cur][2], whb = wts[cur][3];
        const uint4 ct = cor[cur][0];   // top row pair
        const uint4 cb = cor[cur][1];   // bottom row pair
        uint4 A4;
        A4.x = blend2_fp8<false>(ct.x, ct.z, cb.x, cb.z, wlt, wht, wlb, whb);
        A4.y = blend2_fp8<true >(ct.x, ct.z, cb.x, cb.z, wlt, wht, wlb, whb);
        A4.z = blend2_fp8<false>(ct.y, ct.w, cb.y, cb.w, wlt, wht, wlb, whb);
        A4.w = blend2_fp8<true >(ct.y, ct.w, cb.y, cb.w, wlt, wht, wlb, whb);
        U4H8 ca; ca.u = A4;

        acc[g] = __builtin_amdgcn_mfma_f32_16x16x32_f16(ca.h, bfr[kkb],
                                                        acc[g], 0, 0, 0);
    }
#undef PREP

    float d0 = acc[0][0] - tv0.x, d1 = acc[0][1] - tv0.y,
          d2 = acc[0][2] - tv0.z, d3 = acc[0][3] - tv0.w;
    float e0 = acc[1][0] - tv1.x, e1 = acc[1][1] - tv1.y,
          e2 = acc[1][2] - tv1.z, e3 = acc[1][3] - tv1.w;
    float part = (d0 * d0 + d1 * d1 + d2 * d2 + d3 * d3
                + e0 * e0 + e1 * e1 + e2 * e2 + e3 * e3)
               * (1.0f / (float)((size_t)B_ * CO_ * HW_));

#pragma unroll
    for (int sft = 32; sft > 0; sft >>= 1)
        part += __shfl_down(part, sft, 64);

    __shared__ float red[4];
    __shared__ int finflag;
    if (l == 0)
        red[t >> 6] = part;
    __syncthreads();
    unsigned* cnt = (unsigned*)(partials + NBLK);
    if (t == 0) {
        const float p4 = red[0] + red[1] + red[2] + red[3];
        // release-store partial to the coherent point (cross-XCD visible)
        __hip_atomic_store(&partials[blockIdx.x], p4, __ATOMIC_RELEASE,
                           __HIP_MEMORY_SCOPE_AGENT);
        int fin = 0;
        const unsigned o1 = __hip_atomic_fetch_add(
            &cnt[blockIdx.x >> 6], 1u, __ATOMIC_ACQ_REL,
            __HIP_MEMORY_SCOPE_AGENT);
        if (o1 == 63u) {
            const unsigned o2 = __hip_atomic_fetch_add(
                &cnt[32], 1u, __ATOMIC_ACQ_REL, __HIP_MEMORY_SCOPE_AGENT);
            if (o2 == 31u) fin = 1;
        }
        finflag = fin;
    }
    __syncthreads();
    if (finflag) {
        // last block: all 2048 partials are visible (acq/rel chain)
        float s = 0.f;
#pragma unroll
        for (int i = 0; i < NBLK / 256; i++)
            s += __hip_atomic_load(&partials[t + i * 256], __ATOMIC_ACQUIRE,
                                   __HIP_MEMORY_SCOPE_AGENT);
#pragma unroll
        for (int sft = 32; sft > 0; sft >>= 1)
            s += __shfl_down(s, sft, 64);
        if (l == 0) red[t >> 6] = s;
        __syncthreads();
        if (t == 0) out[0] = red[0] + red[1] + red[2] + red[3];
    }
}

// ------- Fallback (round-1 NCHW kernel, used if ws too small) --------------
__global__ __launch_bounds__(256) void deform_loss_kernel(
    const float* __restrict__ off, const float* __restrict__ inp,
    const float* __restrict__ ker, const float* __restrict__ tgt,
    float* __restrict__ out)
{
    const int idx = blockIdx.x * blockDim.x + threadIdx.x;
    float part = 0.f;
    if (idx < B_ * H_ * W_) {
        const int w  = idx & (W_ - 1);
        const int h  = (idx >> 8) & (H_ - 1);
        const int b  = idx >> 16;
        const int hw = h * W_ + w;
        const float* offb = off + (size_t)b * (2 * KK_ * HW_);
        const float* inpb = inp + (size_t)b * (C_ * HW_);
        float acc[CO_];
#pragma unroll
        for (int o = 0; o < CO_; o++) acc[o] = 0.f;
        for (int kk = 0; kk < KK_; kk++) {
            const float dy = offb[(2 * kk)     * HW_ + hw];
            const float dx = offb[(2 * kk + 1) * HW_ + hw];
            const float y = dy + (float)(h - 1 + kk / KS_);
            const float x = dx + (float)(w - 1 + kk % KS_);
            const float y0f = floorf(y);
            const float x0f = floorf(x);
            const int   y0  = (int)y0f;
            const int   x0  = (int)x0f;
            const float wy  = y - y0f;
            const float wx  = x - x0f;
            float w00 = (1.f - wy) * (1.f - wx);
            float w01 = (1.f - wy) * wx;
            float w10 = wy * (1.f - wx);
            float w11 = wy * wx;
            const bool v0y = ((unsigned)y0       < (unsigned)H_);
            const bool v1y = ((unsigned)(y0 + 1) < (unsigned)H_);
            const bool v0x = ((unsigned)x0       < (unsigned)W_);
            const bool v1x = ((unsigned)(x0 + 1) < (unsigned)W_);
            w00 = (v0y & v0x) ? w00 : 0.f;
            w01 = (v0y & v1x) ? w01 : 0.f;
            w10 = (v1y & v0x) ? w10 : 0.f;
            w11 = (v1y & v1x) ? w11 : 0.f;
            const int i00 = min(max(y0,0),H_-1)*W_ + min(max(x0,0),W_-1);
            const int i01 = min(max(y0,0),H_-1)*W_ + min(max(x0+1,0),W_-1);
            const int i10 = min(max(y0+1,0),H_-1)*W_ + min(max(x0,0),W_-1);
            const int i11 = min(max(y0+1,0),H_-1)*W_ + min(max(x0+1,0),W_-1);
            for (int c = 0; c < C_; c++) {
                const float* pp = inpb + c * HW_;
                const float s = pp[i00]*w00 + pp[i01]*w01 + pp[i10]*w10 + pp[i11]*w11;
#pragma unroll
                for (int o = 0; o < CO_; o++)
                    acc[o] = fmaf(s, ker[(o * C_ + c) * KK_ + kk], acc[o]);
            }
        }
        const float* tb = tgt + (size_t)b * (CO_ * HW_);
#pragma unroll
        for (int o = 0; o < CO_; o++) {
            const float d = acc[o] - tb[o * HW_ + hw];
            part = fmaf(d, d, part);
        }
        part *= (1.0f / (float)((size_t)B_ * CO_ * HW_));
    }
#pragma unroll
    for (int sft = 32; sft > 0; sft >>= 1)
        part += __shfl_down(part, sft, 64);
    if ((threadIdx.x & 63) == 0)
        atomicAdd(out, part);
}

extern "C" void kernel_launch(void* const* d_in, const int* in_sizes, int n_in,
                              void* d_out, int out_size, void* d_ws, size_t ws_size,
                              hipStream_t stream) {
    const float* offsets = (const float*)d_in[0];
    const float* input   = (const float*)d_in[1];
    const float* ker     = (const float*)d_in[2];
    const float* target  = (const float*)d_in[3];
    float* out = (float*)d_out;

    const size_t need = (CNT_OFF + 64) * sizeof(unsigned);
    if (ws_size >= need) {
        unsigned* wsu = (unsigned*)d_ws;
        // pack (also zeroes done-counters); 256 blocks x 4 px/thread
        pack_nhwc_fp8<<<(B_ * HW_) / 1024, 256, 0, stream>>>(input, ker, wsu);
        // deform + fused final reduction: 2 dispatches total
        deform_loss_mfma<<<NBLK, 256, 0, stream>>>(
            offsets, wsu, target, (float*)(wsu + PART_OFF), out);
    } else {
        hipMemsetAsync(out, 0, sizeof(float), stream);
        const int total = B_ * H_ * W_;
        deform_loss_kernel<<<(total + 255) / 256, 256, 0, stream>>>(
            offsets, input, ker, target, out);
    }
}

// Round 14
// 108.242 us; speedup vs baseline: 1.9315x; 1.9315x over previous
//
#include <hip/hip_runtime.h>
#include <hip/hip_fp16.h>

#define B_  4
#define C_  16
#define H_  256
#define W_  256
#define CO_ 16
#define KS_ 3
#define KK_ 9
#define HW_ (H_ * W_)
// ws layout (u32 words): fp8 image, TWO half-planes of 8 B/pixel | kbuf | parts
#define IMG_WORDS ((size_t)B_ * HW_ * 4)   // 16 B per pixel total (fp8 e4m3)
#define KER_OFF   IMG_WORDS
#define NKB 5                               // k-blocks per group: K=160
#define NBLK 2048                           // blocks: 128 pixels each
#define PART_OFF (KER_OFF + (size_t)NKB * 256)

typedef _Float16 f16x8 __attribute__((ext_vector_type(8)));
typedef __fp16   fp16x2 __attribute__((ext_vector_type(2)));  // cvt_pkrtz ret
typedef float    f32x2v __attribute__((ext_vector_type(2)));
typedef __attribute__((ext_vector_type(4))) float f32x4;
union U4H8 { uint4 u; f16x8 h; };

// 16B load from an 8B-aligned address (pair of adjacent 8B half-records).
__device__ __forceinline__ uint4 ld16(const uint2* p) {
    uint4 r; __builtin_memcpy(&r, p, sizeof(uint4)); return r;
}

// ------- Kernel 1: NCHW fp32 -> fp8 HALF-PLANE pack (4 px/thread) ----------
// Image stored as two planes: plane h holds channels [8h, 8h+8) of every
// pixel, 8 B/pixel contiguous -> deform fetches each bilinear x-pair with
// ONE dwordx4 (r12 win: transaction count, not bytes, bounds deform).
// 4 pixels/thread with float4 plane loads: 16 dwordx4 loads + 4 dwordx4
// stores replace 64 scalar loads + 8 stores. Block mapping XCD-aligned with
// deform (same bx&7 bijection). NO device-scope fences anywhere (r13 lesson:
// per-block agent-scope release/acquire = L2 writeback storm, 10x regression
// — the kernel boundary is the only cheap global fence).
__global__ __launch_bounds__(256) void pack_nhwc_fp8(
    const float* __restrict__ inp, const float* __restrict__ ker,
    unsigned* __restrict__ wsu)
{
    const int t = threadIdx.x;
    // bijection on [0,256): XCD x=bx&7 covers 1024-px chunks [x*32,(x+1)*32)
    const int j = (blockIdx.x & 7) * 32 + (blockIdx.x >> 3);
    const int e = j * 1024 + t * 4;         // first of this thread's 4 pixels
    const int b = e >> 16;
    const int hw = e & (HW_ - 1);
    const float* src = inp + (size_t)b * (C_ * HW_) + hw;
    f32x4 v[C_];
#pragma unroll
    for (int c = 0; c < C_; c++)
        v[c] = *(const f32x4*)(src + (size_t)c * HW_);   // 16 B coalesced
    unsigned pw0[8], pw1[8];
#pragma unroll
    for (int p = 0; p < 4; p++) {
        unsigned u[4];
#pragma unroll
        for (int d = 0; d < 4; d++) {
            unsigned w = 0;
            w = __builtin_amdgcn_cvt_pk_fp8_f32(v[4*d+0][p], v[4*d+1][p], w, false);
            w = __builtin_amdgcn_cvt_pk_fp8_f32(v[4*d+2][p], v[4*d+3][p], w, true);
            u[d] = w;
        }
        pw0[2*p] = u[0]; pw0[2*p+1] = u[1];   // plane 0: ch 0-7
        pw1[2*p] = u[2]; pw1[2*p+1] = u[3];   // plane 1: ch 8-15
    }
    uint4* d0 = (uint4*)((uint2*)wsu + e);
    d0[0] = make_uint4(pw0[0], pw0[1], pw0[2], pw0[3]);
    d0[1] = make_uint4(pw0[4], pw0[5], pw0[6], pw0[7]);
    uint4* d1 = (uint4*)((uint2*)wsu + (size_t)B_ * HW_ + e);
    d1[0] = make_uint4(pw1[0], pw1[1], pw1[2], pw1[3]);
    d1[1] = make_uint4(pw1[4], pw1[5], pw1[6], pw1[7]);

    if (blockIdx.x == 0) {
        // kbuf: f16 B-fragment layout for mfma_f32_16x16x32_f16 (unchanged).
        //   B[k][n]: k = (lane>>4)*8 + j, n = o = lane&15,
        //   tap = 2*blk + (k>>4), c = k&15; zero when tap > 8 (K padding).
        for (int i = t; i < NKB * 256; i += 256) {
            const int wj  = i & 3;
            const int l   = (i >> 2) & 63;
            const int blk = i >> 8;
            const int o   = l & 15;
            unsigned lo = 0, hi = 0;
            {
                int jj = 2 * wj, k = (l >> 4) * 8 + jj;
                int tap = 2 * blk + (k >> 4), c = k & 15;
                if (tap <= 8) {
                    __half hh = __float2half(ker[(o * C_ + c) * KK_ + tap]);
                    lo = __half_as_ushort(hh);
                }
                jj = 2 * wj + 1; k = (l >> 4) * 8 + jj;
                tap = 2 * blk + (k >> 4); c = k & 15;
                if (tap <= 8) {
                    __half hh = __float2half(ker[(o * C_ + c) * KK_ + tap]);
                    hi = __half_as_ushort(hh);
                }
            }
            wsu[KER_OFF + i] = lo | (hi << 16);
        }
    }
}

// ------- tap setup, pair form (r12, unchanged) ------------------------------
__device__ __forceinline__ void tap_setup_pair(
    int h, int w, int kk, float dy, float dx,
    int* ridx, float* wt)
{
    const float y = dy + (float)(h - 1 + kk / KS_);
    const float x = dx + (float)(w - 1 + kk % KS_);
    const float y0f = floorf(y);
    const float x0f = floorf(x);
    const int   y0  = (int)y0f;
    const int   x0  = (int)x0f;
    const float wy  = y - y0f;
    const float wx  = x - x0f;

    float w00 = (1.f - wy) * (1.f - wx);
    float w01 = (1.f - wy) * wx;
    float w10 = wy * (1.f - wx);
    float w11 = wy * wx;

    const bool v0y = ((unsigned)y0       < (unsigned)H_);
    const bool v1y = ((unsigned)(y0 + 1) < (unsigned)H_);
    const bool v0x = ((unsigned)x0       < (unsigned)W_);
    const bool v1x = ((unsigned)(x0 + 1) < (unsigned)W_);

    w00 = (v0y & v0x) ? w00 : 0.f;
    w01 = (v0y & v1x) ? w01 : 0.f;
    w10 = (v1y & v0x) ? w10 : 0.f;
    w11 = (v1y & v1x) ? w11 : 0.f;

    const int  p    = min(max(x0, 0), W_ - 2);
    const bool s0hi = (x0 >= W_ - 1);   // corner x0   -> hi slot (right edge)
    const bool s1lo = (x0 <= -1);       // corner x0+1 -> lo slot (left edge)

    wt[0] = (s0hi ? 0.f : w00) + (s1lo ? w01 : 0.f);
    wt[1] = (s0hi ? w00 : 0.f) + (s1lo ? 0.f : w01);
    wt[2] = (s0hi ? 0.f : w10) + (s1lo ? w11 : 0.f);
    wt[3] = (s0hi ? w10 : 0.f) + (s1lo ? 0.f : w11);

    const int y0c = min(max(y0,     0), H_ - 1);
    const int y1c = min(max(y0 + 1, 0), H_ - 1);
    ridx[0] = y0c * W_ + p;
    ridx[1] = y1c * W_ + p;
}

// fp8 corner blend, one output word (2 channels): 4 cvt_pk_f32_fp8 +
// 8 f32 fma + 1 cvt_pkrtz. f32 blend = single rounding.
template<bool HI>
__device__ __forceinline__ unsigned blend2_fp8(
    unsigned a, unsigned b, unsigned c, unsigned d,
    float w0, float w1, float w2, float w3)
{
    const f32x2v va = __builtin_amdgcn_cvt_pk_f32_fp8(a, HI);
    const f32x2v vb = __builtin_amdgcn_cvt_pk_f32_fp8(b, HI);
    const f32x2v vc = __builtin_amdgcn_cvt_pk_f32_fp8(c, HI);
    const f32x2v vd = __builtin_amdgcn_cvt_pk_f32_fp8(d, HI);
    const float rl = w0 * va.x + w1 * vb.x + w2 * vc.x + w3 * vd.x;
    const float rh = w0 * va.y + w1 * vb.y + w2 * vc.y + w3 * vd.y;
    union { fp16x2 h; unsigned u; } cv;
    cv.h = __builtin_amdgcn_cvt_pkrtz(rl, rh);
    return cv.u;
}

// ------- Kernel 2: deform-conv + MSE via MFMA, 2 groups/wave, no atomics ---
// Wave = 2 groups x 16 pixels x 4 k-quads. Lane(q,m) reads its channel-half
// plane; each bilinear x-pair is ONE dwordx4 (r12 win). Prefetch-2 (r7 win).
// Plain per-block store ending (r13 lesson: NO per-block device-scope
// fences — they trigger an L2 writeback storm).
__global__ __launch_bounds__(256) void deform_loss_mfma(
    const float* __restrict__ off, const unsigned* __restrict__ wsu,
    const float* __restrict__ tgt, float* __restrict__ partials)
{
    // XCD swizzle: bijection on [0,2048); xcd = blk&7 covers 256 consecutive
    // 128-pixel blocks = 128 contiguous rows -> per-XCD L2 locality
    const int f = (blockIdx.x & 7) * 256 + (blockIdx.x >> 3);
    const int t = threadIdx.x;
    const int l = t & 63;
    const int q = l >> 4;
    const int m = l & 15;
    const int base = f * 128 + (t >> 6) * 32;   // wave's 32-pixel span
    const int b    = base >> 16;                // span never crosses b
    const int hwb  = base & (HW_ - 1);
    const int h    = hwb >> 8;                  // same row for both groups
    const int w0   = (hwb & (W_ - 1)) + m;      // group g pixel w = w0+16g

    const float* offp = off + (size_t)b * (2 * KK_ * HW_) + (size_t)h * W_;
    const uint2* ibh  = (const uint2*)wsu
                      + (size_t)(q & 1) * (B_ * HW_) + (size_t)b * HW_;
    const uint4* kb   = (const uint4*)(wsu + KER_OFF);

    // B-fragments: 5 x 16 B f16, register-resident (unchanged)
    f16x8 bfr[NKB];
#pragma unroll
    for (int kbk = 0; kbk < NKB; kbk++) {
        U4H8 cv; cv.u = kb[kbk * 64 + l];
        bfr[kbk] = cv.h;
    }

    // ALL entry loads issued together: 20 offsets + 2 target float4s.
    // tap>8 clamped to 8: valid memory; contribution zeroed by B=0 padding.
    float dyv[2][NKB], dxv[2][NKB];
#pragma unroll
    for (int g = 0; g < 2; g++)
#pragma unroll
        for (int kbk = 0; kbk < NKB; kbk++) {
            const int tap = min(2 * kbk + (q >> 1), KK_ - 1);
            dyv[g][kbk] = offp[(size_t)(2 * tap) * HW_ + w0 + 16 * g];
            dxv[g][kbk] = offp[(size_t)(2 * tap + 1) * HW_ + w0 + 16 * g];
        }
    // targets (C/D layout: col=lane&15=o, row=4q+reg=pixel-in-group)
    const float* tbase = tgt + (size_t)b * (CO_ * HW_) + (size_t)m * HW_
                       + hwb + 4 * q;
    const float4 tv0 = *(const float4*)(tbase);
    const float4 tv1 = *(const float4*)(tbase + 16);

    f32x4 acc[2] = {{0.f, 0.f, 0.f, 0.f}, {0.f, 0.f, 0.f, 0.f}};
    uint4 cor[3][2];        // [slot][row]: .xy = lo record, .zw = hi record
    float wts[3][4];

    // PREP(KBI, SLOT): tap_setup_pair + pad-collapse + 2 dwordx4 gathers.
    // K-padding lanes (tap 9, kn==NKB-1 && q>=2): B-frag is 0, so collapse
    // their gathers onto records 0-1 (broadcast) with wt=0.
#define PREP(KBI, SLOT) do {                                               \
        const int gn_ = (KBI) / NKB, kn_ = (KBI) % NKB;                    \
        int ridx_[2];                                                      \
        tap_setup_pair(h, w0 + 16 * gn_, min(2 * kn_ + (q >> 1), KK_ - 1), \
                       dyv[gn_][kn_], dxv[gn_][kn_], ridx_, wts[SLOT]);    \
        if (kn_ == NKB - 1 && (q >> 1) != 0) {                             \
            wts[SLOT][0] = 0.f; wts[SLOT][1] = 0.f;                        \
            wts[SLOT][2] = 0.f; wts[SLOT][3] = 0.f;                        \
            ridx_[0] = 0; ridx_[1] = 0;                                    \
        }                                                                  \
        cor[SLOT][0] = ld16(ibh + ridx_[0]);                               \
        cor[SLOT][1] = ld16(ibh + ridx_[1]);                               \
    } while (0)

    // prologue: fill slots 0 and 1 (kbi = 0, 1 — never padding blocks)
    PREP(0, 0);
    PREP(1, 1);

#pragma unroll
    for (int kbi = 0; kbi < 2 * NKB; kbi++) {
        const int cur = kbi % 3;
        if (kbi + 2 < 2 * NKB)
            PREP(kbi + 2, (kbi + 2) % 3);

        const int g = kbi / NKB;
        const int kkb = kbi % NKB;
        const float wlt = wts[cur][0], wht = wts[cur][1],
                    wlb = wts[cur][2], whb = wts[cur][3];
        const uint4 ct = cor[cur][0];   // top row pair
        const uint4 cb = cor[cur][1];   // bottom row pair
        uint4 A4;
        A4.x = blend2_fp8<false>(ct.x, ct.z, cb.x, cb.z, wlt, wht, wlb, whb);
        A4.y = blend2_fp8<true >(ct.x, ct.z, cb.x, cb.z, wlt, wht, wlb, whb);
        A4.z = blend2_fp8<false>(ct.y, ct.w, cb.y, cb.w, wlt, wht, wlb, whb);
        A4.w = blend2_fp8<true >(ct.y, ct.w, cb.y, cb.w, wlt, wht, wlb, whb);
        U4H8 ca; ca.u = A4;

        acc[g] = __builtin_amdgcn_mfma_f32_16x16x32_f16(ca.h, bfr[kkb],
                                                        acc[g], 0, 0, 0);
    }
#undef PREP

    float d0 = acc[0][0] - tv0.x, d1 = acc[0][1] - tv0.y,
          d2 = acc[0][2] - tv0.z, d3 = acc[0][3] - tv0.w;
    float e0 = acc[1][0] - tv1.x, e1 = acc[1][1] - tv1.y,
          e2 = acc[1][2] - tv1.z, e3 = acc[1][3] - tv1.w;
    float part = (d0 * d0 + d1 * d1 + d2 * d2 + d3 * d3
                + e0 * e0 + e1 * e1 + e2 * e2 + e3 * e3)
               * (1.0f / (float)((size_t)B_ * CO_ * HW_));

    // wave reduce -> LDS -> ONE plain store per block (no atomics, no fences)
#pragma unroll
    for (int sft = 32; sft > 0; sft >>= 1)
        part += __shfl_down(part, sft, 64);

    __shared__ float red[4];
    if (l == 0)
        red[t >> 6] = part;
    __syncthreads();
    if (t == 0)
        partials[blockIdx.x] = red[0] + red[1] + red[2] + red[3];
}

// ------- Kernel 3: sum NBLK block partials -> out --------------------------
__global__ __launch_bounds__(256) void reduce_partials(
    const float* __restrict__ partials, float* __restrict__ out)
{
    const int t = threadIdx.x;
    float s = 0.f;
#pragma unroll
    for (int i = 0; i < NBLK / 256; i++)
        s += partials[t + i * 256];
#pragma unroll
    for (int sft = 32; sft > 0; sft >>= 1)
        s += __shfl_down(s, sft, 64);
    __shared__ float red[4];
    if ((t & 63) == 0) red[t >> 6] = s;
    __syncthreads();
    if (t == 0) out[0] = red[0] + red[1] + red[2] + red[3];
}

// ------- Fallback (round-1 NCHW kernel, used if ws too small) --------------
__global__ __launch_bounds__(256) void deform_loss_kernel(
    const float* __restrict__ off, const float* __restrict__ inp,
    const float* __restrict__ ker, const float* __restrict__ tgt,
    float* __restrict__ out)
{
    const int idx = blockIdx.x * blockDim.x + threadIdx.x;
    float part = 0.f;
    if (idx < B_ * H_ * W_) {
        const int w  = idx & (W_ - 1);
        const int h  = (idx >> 8) & (H_ - 1);
        const int b  = idx >> 16;
        const int hw = h * W_ + w;
        const float* offb = off + (size_t)b * (2 * KK_ * HW_);
        const float* inpb = inp + (size_t)b * (C_ * HW_);
        float acc[CO_];
#pragma unroll
        for (int o = 0; o < CO_; o++) acc[o] = 0.f;
        for (int kk = 0; kk < KK_; kk++) {
            const float dy = offb[(2 * kk)     * HW_ + hw];
            const float dx = offb[(2 * kk + 1) * HW_ + hw];
            const float y = dy + (float)(h - 1 + kk / KS_);
            const float x = dx + (float)(w - 1 + kk % KS_);
            const float y0f = floorf(y);
            const float x0f = floorf(x);
            const int   y0  = (int)y0f;
            const int   x0  = (int)x0f;
            const float wy  = y - y0f;
            const float wx  = x - x0f;
            float w00 = (1.f - wy) * (1.f - wx);
            float w01 = (1.f - wy) * wx;
            float w10 = wy * (1.f - wx);
            float w11 = wy * wx;
            const bool v0y = ((unsigned)y0       < (unsigned)H_);
            const bool v1y = ((unsigned)(y0 + 1) < (unsigned)H_);
            const bool v0x = ((unsigned)x0       < (unsigned)W_);
            const bool v1x = ((unsigned)(x0 + 1) < (unsigned)W_);
            w00 = (v0y & v0x) ? w00 : 0.f;
            w01 = (v0y & v1x) ? w01 : 0.f;
            w10 = (v1y & v0x) ? w10 : 0.f;
            w11 = (v1y & v1x) ? w11 : 0.f;
            const int i00 = min(max(y0,0),H_-1)*W_ + min(max(x0,0),W_-1);
            const int i01 = min(max(y0,0),H_-1)*W_ + min(max(x0+1,0),W_-1);
            const int i10 = min(max(y0+1,0),H_-1)*W_ + min(max(x0,0),W_-1);
            const int i11 = min(max(y0+1,0),H_-1)*W_ + min(max(x0+1,0),W_-1);
            for (int c = 0; c < C_; c++) {
                const float* pp = inpb + c * HW_;
                const float s = pp[i00]*w00 + pp[i01]*w01 + pp[i10]*w10 + pp[i11]*w11;
#pragma unroll
                for (int o = 0; o < CO_; o++)
                    acc[o] = fmaf(s, ker[(o * C_ + c) * KK_ + kk], acc[o]);
            }
        }
        const float* tb = tgt + (size_t)b * (CO_ * HW_);
#pragma unroll
        for (int o = 0; o < CO_; o++) {
            const float d = acc[o] - tb[o * HW_ + hw];
            part = fmaf(d, d, part);
        }
        part *= (1.0f / (float)((size_t)B_ * CO_ * HW_));
    }
#pragma unroll
    for (int sft = 32; sft > 0; sft >>= 1)
        part += __shfl_down(part, sft, 64);
    if ((threadIdx.x & 63) == 0)
        atomicAdd(out, part);
}

extern "C" void kernel_launch(void* const* d_in, const int* in_sizes, int n_in,
                              void* d_out, int out_size, void* d_ws, size_t ws_size,
                              hipStream_t stream) {
    const float* offsets = (const float*)d_in[0];
    const float* input   = (const float*)d_in[1];
    const float* ker     = (const float*)d_in[2];
    const float* target  = (const float*)d_in[3];
    float* out = (float*)d_out;

    const size_t need = (PART_OFF + NBLK) * sizeof(unsigned);
    if (ws_size >= need) {
        unsigned* wsu = (unsigned*)d_ws;
        // pack: 256 blocks x 4 px/thread (vectorized float4 plane loads)
        pack_nhwc_fp8<<<(B_ * HW_) / 1024, 256, 0, stream>>>(input, ker, wsu);
        // 2048 blocks x 256 threads: wave = 2 groups x 16 pixels x 4 k-quads
        deform_loss_mfma<<<NBLK, 256, 0, stream>>>(
            offsets, wsu, target, (float*)(wsu + PART_OFF));
        reduce_partials<<<1, 256, 0, stream>>>(
            (const float*)(wsu + PART_OFF), out);
    } else {
        hipMemsetAsync(out, 0, sizeof(float), stream);
        const int total = B_ * H_ * W_;
        deform_loss_kernel<<<(total + 255) / 256, 256, 0, stream>>>(
            offsets, input, ker, target, out);
    }
}

// Round 15
// 107.199 us; speedup vs baseline: 1.9503x; 1.0097x over previous
//
#include <hip/hip_runtime.h>
#include <hip/hip_fp16.h>

#define B_  4
#define C_  16
#define H_  256
#define W_  256
#define CO_ 16
#define KS_ 3
#define KK_ 9
#define HW_ (H_ * W_)
// ws layout (u32 words): fp8 image, TWO half-planes of 8 B/pixel | kbuf | parts
#define IMG_WORDS ((size_t)B_ * HW_ * 4)   // 16 B per pixel total (fp8 e4m3)
#define KER_OFF   IMG_WORDS
#define NKB 5                               // k-blocks per group: K=160
#define NBLK 2048                           // blocks: 128 pixels each
#define PART_OFF (KER_OFF + (size_t)NKB * 256)

typedef _Float16 f16x8 __attribute__((ext_vector_type(8)));
typedef __fp16   fp16x2 __attribute__((ext_vector_type(2)));  // cvt_pkrtz ret
typedef float    f32x2v __attribute__((ext_vector_type(2)));
typedef __attribute__((ext_vector_type(4))) float f32x4;
union U4H8 { uint4 u; f16x8 h; };

// 16B load from an 8B-aligned address (pair of adjacent 8B half-records).
__device__ __forceinline__ uint4 ld16(const uint2* p) {
    uint4 r; __builtin_memcpy(&r, p, sizeof(uint4)); return r;
}

// ------- Kernel 1: NCHW fp32 -> fp8 HALF-PLANE pack (4 px/thread) ----------
// Image stored as two planes: plane h holds channels [8h, 8h+8) of every
// pixel, 8 B/pixel contiguous -> deform fetches each bilinear x-pair with
// ONE dwordx4 (r12 win: transaction count, not bytes, bounds deform).
// 4 pixels/thread with float4 plane loads (r14 win). Block mapping
// XCD-aligned with deform (same bx&7 bijection). NO device-scope fences
// anywhere (r13 lesson: per-block agent-scope release/acquire = L2
// writeback storm, 10x regression).
__global__ __launch_bounds__(256) void pack_nhwc_fp8(
    const float* __restrict__ inp, const float* __restrict__ ker,
    unsigned* __restrict__ wsu)
{
    const int t = threadIdx.x;
    // bijection on [0,256): XCD x=bx&7 covers 1024-px chunks [x*32,(x+1)*32)
    const int j = (blockIdx.x & 7) * 32 + (blockIdx.x >> 3);
    const int e = j * 1024 + t * 4;         // first of this thread's 4 pixels
    const int b = e >> 16;
    const int hw = e & (HW_ - 1);
    const float* src = inp + (size_t)b * (C_ * HW_) + hw;
    f32x4 v[C_];
#pragma unroll
    for (int c = 0; c < C_; c++)
        v[c] = *(const f32x4*)(src + (size_t)c * HW_);   // 16 B coalesced
    unsigned pw0[8], pw1[8];
#pragma unroll
    for (int p = 0; p < 4; p++) {
        unsigned u[4];
#pragma unroll
        for (int d = 0; d < 4; d++) {
            unsigned w = 0;
            w = __builtin_amdgcn_cvt_pk_fp8_f32(v[4*d+0][p], v[4*d+1][p], w, false);
            w = __builtin_amdgcn_cvt_pk_fp8_f32(v[4*d+2][p], v[4*d+3][p], w, true);
            u[d] = w;
        }
        pw0[2*p] = u[0]; pw0[2*p+1] = u[1];   // plane 0: ch 0-7
        pw1[2*p] = u[2]; pw1[2*p+1] = u[3];   // plane 1: ch 8-15
    }
    uint4* d0 = (uint4*)((uint2*)wsu + e);
    d0[0] = make_uint4(pw0[0], pw0[1], pw0[2], pw0[3]);
    d0[1] = make_uint4(pw0[4], pw0[5], pw0[6], pw0[7]);
    uint4* d1 = (uint4*)((uint2*)wsu + (size_t)B_ * HW_ + e);
    d1[0] = make_uint4(pw1[0], pw1[1], pw1[2], pw1[3]);
    d1[1] = make_uint4(pw1[4], pw1[5], pw1[6], pw1[7]);

    if (blockIdx.x == 0) {
        // kbuf: f16 B-fragment layout for mfma_f32_16x16x32_f16 (unchanged).
        //   B[k][n]: k = (lane>>4)*8 + j, n = o = lane&15,
        //   tap = 2*blk + (k>>4), c = k&15; zero when tap > 8 (K padding).
        for (int i = t; i < NKB * 256; i += 256) {
            const int wj  = i & 3;
            const int l   = (i >> 2) & 63;
            const int blk = i >> 8;
            const int o   = l & 15;
            unsigned lo = 0, hi = 0;
            {
                int jj = 2 * wj, k = (l >> 4) * 8 + jj;
                int tap = 2 * blk + (k >> 4), c = k & 15;
                if (tap <= 8) {
                    __half hh = __float2half(ker[(o * C_ + c) * KK_ + tap]);
                    lo = __half_as_ushort(hh);
                }
                jj = 2 * wj + 1; k = (l >> 4) * 8 + jj;
                tap = 2 * blk + (k >> 4); c = k & 15;
                if (tap <= 8) {
                    __half hh = __float2half(ker[(o * C_ + c) * KK_ + tap]);
                    hi = __half_as_ushort(hh);
                }
            }
            wsu[KER_OFF + i] = lo | (hi << 16);
        }
    }
}

// ------- tap setup, pair form (r12, unchanged) ------------------------------
__device__ __forceinline__ void tap_setup_pair(
    int h, int w, int kk, float dy, float dx,
    int* ridx, float* wt)
{
    const float y = dy + (float)(h - 1 + kk / KS_);
    const float x = dx + (float)(w - 1 + kk % KS_);
    const float y0f = floorf(y);
    const float x0f = floorf(x);
    const int   y0  = (int)y0f;
    const int   x0  = (int)x0f;
    const float wy  = y - y0f;
    const float wx  = x - x0f;

    float w00 = (1.f - wy) * (1.f - wx);
    float w01 = (1.f - wy) * wx;
    float w10 = wy * (1.f - wx);
    float w11 = wy * wx;

    const bool v0y = ((unsigned)y0       < (unsigned)H_);
    const bool v1y = ((unsigned)(y0 + 1) < (unsigned)H_);
    const bool v0x = ((unsigned)x0       < (unsigned)W_);
    const bool v1x = ((unsigned)(x0 + 1) < (unsigned)W_);

    w00 = (v0y & v0x) ? w00 : 0.f;
    w01 = (v0y & v1x) ? w01 : 0.f;
    w10 = (v1y & v0x) ? w10 : 0.f;
    w11 = (v1y & v1x) ? w11 : 0.f;

    const int  p    = min(max(x0, 0), W_ - 2);
    const bool s0hi = (x0 >= W_ - 1);   // corner x0   -> hi slot (right edge)
    const bool s1lo = (x0 <= -1);       // corner x0+1 -> lo slot (left edge)

    wt[0] = (s0hi ? 0.f : w00) + (s1lo ? w01 : 0.f);
    wt[1] = (s0hi ? w00 : 0.f) + (s1lo ? 0.f : w01);
    wt[2] = (s0hi ? 0.f : w10) + (s1lo ? w11 : 0.f);
    wt[3] = (s0hi ? w10 : 0.f) + (s1lo ? 0.f : w11);

    const int y0c = min(max(y0,     0), H_ - 1);
    const int y1c = min(max(y0 + 1, 0), H_ - 1);
    ridx[0] = y0c * W_ + p;
    ridx[1] = y1c * W_ + p;
}

// fp8 corner blend, one output word (2 channels): 4 cvt_pk_f32_fp8 +
// 8 f32 fma + 1 cvt_pkrtz. f32 blend = single rounding.
template<bool HI>
__device__ __forceinline__ unsigned blend2_fp8(
    unsigned a, unsigned b, unsigned c, unsigned d,
    float w0, float w1, float w2, float w3)
{
    const f32x2v va = __builtin_amdgcn_cvt_pk_f32_fp8(a, HI);
    const f32x2v vb = __builtin_amdgcn_cvt_pk_f32_fp8(b, HI);
    const f32x2v vc = __builtin_amdgcn_cvt_pk_f32_fp8(c, HI);
    const f32x2v vd = __builtin_amdgcn_cvt_pk_f32_fp8(d, HI);
    const float rl = w0 * va.x + w1 * vb.x + w2 * vc.x + w3 * vd.x;
    const float rh = w0 * va.y + w1 * vb.y + w2 * vc.y + w3 * vd.y;
    union { fp16x2 h; unsigned u; } cv;
    cv.h = __builtin_amdgcn_cvt_pkrtz(rl, rh);
    return cv.u;
}

// ------- Kernel 2: deform-conv + MSE via MFMA, 2 groups/wave, no atomics ---
// Wave = 2 groups x 16 pixels x 4 k-quads; pair-gather (r12); prefetch-2
// (r7); plain per-block store ending (r13 lesson).
// NEW (r15): offset loads shared across q-pairs — lanes l and l^16 need
// IDENTICAL dy/dx (they depend only on q>>1, not q&1), so each lane loads
// only its own half-plane value (dy for even q, dx for odd q) and gets the
// partner's via shfl_xor(.,16): 20 -> 10 VMEM insts/lane (transaction
// count is the binding resource — r11/r12 evidence).
__global__ __launch_bounds__(256) void deform_loss_mfma(
    const float* __restrict__ off, const unsigned* __restrict__ wsu,
    const float* __restrict__ tgt, float* __restrict__ partials)
{
    // XCD swizzle: bijection on [0,2048); xcd = blk&7 covers 256 consecutive
    // 128-pixel blocks = 128 contiguous rows -> per-XCD L2 locality
    const int f = (blockIdx.x & 7) * 256 + (blockIdx.x >> 3);
    const int t = threadIdx.x;
    const int l = t & 63;
    const int q = l >> 4;
    const int m = l & 15;
    const int base = f * 128 + (t >> 6) * 32;   // wave's 32-pixel span
    const int b    = base >> 16;                // span never crosses b
    const int hwb  = base & (HW_ - 1);
    const int h    = hwb >> 8;                  // same row for both groups
    const int w0   = (hwb & (W_ - 1)) + m;      // group g pixel w = w0+16g

    const float* offp = off + (size_t)b * (2 * KK_ * HW_) + (size_t)h * W_;
    const uint2* ibh  = (const uint2*)wsu
                      + (size_t)(q & 1) * (B_ * HW_) + (size_t)b * HW_;
    const uint4* kb   = (const uint4*)(wsu + KER_OFF);

    // B-fragments: 5 x 16 B f16, register-resident (unchanged)
    f16x8 bfr[NKB];
#pragma unroll
    for (int kbk = 0; kbk < NKB; kbk++) {
        U4H8 cv; cv.u = kb[kbk * 64 + l];
        bfr[kbk] = cv.h;
    }

    // Entry loads: 10 offset half-values (own q&1 plane) + 2 target float4s.
    // tap>8 clamped to 8: valid memory; contribution zeroed by B=0 padding.
    float own[2][NKB], oth[2][NKB];
#pragma unroll
    for (int g = 0; g < 2; g++)
#pragma unroll
        for (int kbk = 0; kbk < NKB; kbk++) {
            const int tap = min(2 * kbk + (q >> 1), KK_ - 1);
            own[g][kbk] = offp[(size_t)(2 * tap + (q & 1)) * HW_
                               + w0 + 16 * g];
        }
    // partner's half via cross-lane (DS pipe, not VMEM)
#pragma unroll
    for (int g = 0; g < 2; g++)
#pragma unroll
        for (int kbk = 0; kbk < NKB; kbk++)
            oth[g][kbk] = __shfl_xor(own[g][kbk], 16, 64);
    // targets (C/D layout: col=lane&15=o, row=4q+reg=pixel-in-group)
    const float* tbase = tgt + (size_t)b * (CO_ * HW_) + (size_t)m * HW_
                       + hwb + 4 * q;
    const float4 tv0 = *(const float4*)(tbase);
    const float4 tv1 = *(const float4*)(tbase + 16);

    f32x4 acc[2] = {{0.f, 0.f, 0.f, 0.f}, {0.f, 0.f, 0.f, 0.f}};
    uint4 cor[3][2];        // [slot][row]: .xy = lo record, .zw = hi record
    float wts[3][4];

    // PREP(KBI, SLOT): select dy/dx (compile-time indices, 2 cndmask) +
    // tap_setup_pair + pad-collapse + 2 dwordx4 gathers.
    // K-padding lanes (tap 9, kn==NKB-1 && q>=2): B-frag is 0, so collapse
    // their gathers onto records 0-1 (broadcast) with wt=0.
#define PREP(KBI, SLOT) do {                                               \
        const int gn_ = (KBI) / NKB, kn_ = (KBI) % NKB;                    \
        const float dy_ = (q & 1) ? oth[gn_][kn_] : own[gn_][kn_];         \
        const float dx_ = (q & 1) ? own[gn_][kn_] : oth[gn_][kn_];         \
        int ridx_[2];                                                      \
        tap_setup_pair(h, w0 + 16 * gn_, min(2 * kn_ + (q >> 1), KK_ - 1), \
                       dy_, dx_, ridx_, wts[SLOT]);                        \
        if (kn_ == NKB - 1 && (q >> 1) != 0) {                             \
            wts[SLOT][0] = 0.f; wts[SLOT][1] = 0.f;                        \
            wts[SLOT][2] = 0.f; wts[SLOT][3] = 0.f;                        \
            ridx_[0] = 0; ridx_[1] = 0;                                    \
        }                                                                  \
        cor[SLOT][0] = ld16(ibh + ridx_[0]);                               \
        cor[SLOT][1] = ld16(ibh + ridx_[1]);                               \
    } while (0)

    // prologue: fill slots 0 and 1 (kbi = 0, 1 — never padding blocks)
    PREP(0, 0);
    PREP(1, 1);

#pragma unroll
    for (int kbi = 0; kbi < 2 * NKB; kbi++) {
        const int cur = kbi % 3;
        if (kbi + 2 < 2 * NKB)
            PREP(kbi + 2, (kbi + 2) % 3);

        const int g = kbi / NKB;
        const int kkb = kbi % NKB;
        const float wlt = wts[cur][0], wht = wts[cur][1],
                    wlb = wts[cur][2], whb = wts[cur][3];
        const uint4 ct = cor[cur][0];   // top row pair
        const uint4 cb = cor[cur][1];   // bottom row pair
        uint4 A4;
        A4.x = blend2_fp8<false>(ct.x, ct.z, cb.x, cb.z, wlt, wht, wlb, whb);
        A4.y = blend2_fp8<true >(ct.x, ct.z, cb.x, cb.z, wlt, wht, wlb, whb);
        A4.z = blend2_fp8<false>(ct.y, ct.w, cb.y, cb.w, wlt, wht, wlb, whb);
        A4.w = blend2_fp8<true >(ct.y, ct.w, cb.y, cb.w, wlt, wht, wlb, whb);
        U4H8 ca; ca.u = A4;

        acc[g] = __builtin_amdgcn_mfma_f32_16x16x32_f16(ca.h, bfr[kkb],
                                                        acc[g], 0, 0, 0);
    }
#undef PREP

    float d0 = acc[0][0] - tv0.x, d1 = acc[0][1] - tv0.y,
          d2 = acc[0][2] - tv0.z, d3 = acc[0][3] - tv0.w;
    float e0 = acc[1][0] - tv1.x, e1 = acc[1][1] - tv1.y,
          e2 = acc[1][2] - tv1.z, e3 = acc[1][3] - tv1.w;
    float part = (d0 * d0 + d1 * d1 + d2 * d2 + d3 * d3
                + e0 * e0 + e1 * e1 + e2 * e2 + e3 * e3)
               * (1.0f / (float)((size_t)B_ * CO_ * HW_));

    // wave reduce -> LDS -> ONE plain store per block (no atomics, no fences)
#pragma unroll
    for (int sft = 32; sft > 0; sft >>= 1)
        part += __shfl_down(part, sft, 64);

    __shared__ float red[4];
    if (l == 0)
        red[t >> 6] = part;
    __syncthreads();
    if (t == 0)
        partials[blockIdx.x] = red[0] + red[1] + red[2] + red[3];
}

// ------- Kernel 3: sum NBLK block partials -> out --------------------------
__global__ __launch_bounds__(256) void reduce_partials(
    const float* __restrict__ partials, float* __restrict__ out)
{
    const int t = threadIdx.x;
    float s = 0.f;
#pragma unroll
    for (int i = 0; i < NBLK / 256; i++)
        s += partials[t + i * 256];
#pragma unroll
    for (int sft = 32; sft > 0; sft >>= 1)
        s += __shfl_down(s, sft, 64);
    __shared__ float red[4];
    if ((t & 63) == 0) red[t >> 6] = s;
    __syncthreads();
    if (t == 0) out[0] = red[0] + red[1] + red[2] + red[3];
}

// ------- Fallback (round-1 NCHW kernel, used if ws too small) --------------
__global__ __launch_bounds__(256) void deform_loss_kernel(
    const float* __restrict__ off, const float* __restrict__ inp,
    const float* __restrict__ ker, const float* __restrict__ tgt,
    float* __restrict__ out)
{
    const int idx = blockIdx.x * blockDim.x + threadIdx.x;
    float part = 0.f;
    if (idx < B_ * H_ * W_) {
        const int w  = idx & (W_ - 1);
        const int h  = (idx >> 8) & (H_ - 1);
        const int b  = idx >> 16;
        const int hw = h * W_ + w;
        const float* offb = off + (size_t)b * (2 * KK_ * HW_);
        const float* inpb = inp + (size_t)b * (C_ * HW_);
        float acc[CO_];
#pragma unroll
        for (int o = 0; o < CO_; o++) acc[o] = 0.f;
        for (int kk = 0; kk < KK_; kk++) {
            const float dy = offb[(2 * kk)     * HW_ + hw];
            const float dx = offb[(2 * kk + 1) * HW_ + hw];
            const float y = dy + (float)(h - 1 + kk / KS_);
            const float x = dx + (float)(w - 1 + kk % KS_);
            const float y0f = floorf(y);
            const float x0f = floorf(x);
            const int   y0  = (int)y0f;
            const int   x0  = (int)x0f;
            const float wy  = y - y0f;
            const float wx  = x - x0f;
            float w00 = (1.f - wy) * (1.f - wx);
            float w01 = (1.f - wy) * wx;
            float w10 = wy * (1.f - wx);
            float w11 = wy * wx;
            const bool v0y = ((unsigned)y0       < (unsigned)H_);
            const bool v1y = ((unsigned)(y0 + 1) < (unsigned)H_);
            const bool v0x = ((unsigned)x0       < (unsigned)W_);
            const bool v1x = ((unsigned)(x0 + 1) < (unsigned)W_);
            w00 = (v0y & v0x) ? w00 : 0.f;
            w01 = (v0y & v1x) ? w01 : 0.f;
            w10 = (v1y & v0x) ? w10 : 0.f;
            w11 = (v1y & v1x) ? w11 : 0.f;
            const int i00 = min(max(y0,0),H_-1)*W_ + min(max(x0,0),W_-1);
            const int i01 = min(max(y0,0),H_-1)*W_ + min(max(x0+1,0),W_-1);
            const int i10 = min(max(y0+1,0),H_-1)*W_ + min(max(x0,0),W_-1);
            const int i11 = min(max(y0+1,0),H_-1)*W_ + min(max(x0+1,0),W_-1);
            for (int c = 0; c < C_; c++) {
                const float* pp = inpb + c * HW_;
                const float s = pp[i00]*w00 + pp[i01]*w01 + pp[i10]*w10 + pp[i11]*w11;
#pragma unroll
                for (int o = 0; o < CO_; o++)
                    acc[o] = fmaf(s, ker[(o * C_ + c) * KK_ + kk], acc[o]);
            }
        }
        const float* tb = tgt + (size_t)b * (CO_ * HW_);
#pragma unroll
        for (int o = 0; o < CO_; o++) {
            const float d = acc[o] - tb[o * HW_ + hw];
            part = fmaf(d, d, part);
        }
        part *= (1.0f / (float)((size_t)B_ * CO_ * HW_));
    }
#pragma unroll
    for (int sft = 32; sft > 0; sft >>= 1)
        part += __shfl_down(part, sft, 64);
    if ((threadIdx.x & 63) == 0)
        atomicAdd(out, part);
}

extern "C" void kernel_launch(void* const* d_in, const int* in_sizes, int n_in,
                              void* d_out, int out_size, void* d_ws, size_t ws_size,
                              hipStream_t stream) {
    const float* offsets = (const float*)d_in[0];
    const float* input   = (const float*)d_in[1];
    const float* ker     = (const float*)d_in[2];
    const float* target  = (const float*)d_in[3];
    float* out = (float*)d_out;

    const size_t need = (PART_OFF + NBLK) * sizeof(unsigned);
    if (ws_size >= need) {
        unsigned* wsu = (unsigned*)d_ws;
        // pack: 256 blocks x 4 px/thread (vectorized float4 plane loads)
        pack_nhwc_fp8<<<(B_ * HW_) / 1024, 256, 0, stream>>>(input, ker, wsu);
        // 2048 blocks x 256 threads: wave = 2 groups x 16 pixels x 4 k-quads
        deform_loss_mfma<<<NBLK, 256, 0, stream>>>(
            offsets, wsu, target, (float*)(wsu + PART_OFF));
        reduce_partials<<<1, 256, 0, stream>>>(
            (const float*)(wsu + PART_OFF), out);
    } else {
        hipMemsetAsync(out, 0, sizeof(float), stream);
        const int total = B_ * H_ * W_;
        deform_loss_kernel<<<(total + 255) / 256, 256, 0, stream>>>(
            offsets, input, ker, target, out);
    }
}